// Round 16
// baseline (135.543 us; speedup 1.0000x reference)
//
#include <hip/hip_runtime.h>
#include <cstdint>
#include <cstddef>

#define NH     12
#define DH     64
#define CIN    768
#define NPIX   196
#define NB     64
#define ROWS   (NB * NPIX)      // 12544 = 56 * 224 = 49 * 256
#define QKV_OC 2304
#define NKT    12               // 768/64

typedef __attribute__((ext_vector_type(8))) _Float16 f16x8;
typedef __attribute__((ext_vector_type(4))) _Float16 f16x4;
typedef __attribute__((ext_vector_type(4))) float    f32x4;

#define MFMA16 __builtin_amdgcn_mfma_f32_16x16x32_f16

// ---------------------------------------------------------------- weights → fp16
__global__ __launch_bounds__(256) void k_convert_w(const float* __restrict__ wq,
                                                   const float* __restrict__ wp,
                                                   _Float16* __restrict__ out) {
    int i = blockIdx.x * 256 + threadIdx.x;
    const int NQ = QKV_OC * CIN / 4;
    const int NT = NQ + (CIN * CIN) / 4;
    if (i >= NT) return;
    float4 v = (i < NQ) ? ((const float4*)wq)[i] : ((const float4*)wp)[i - NQ];
    f16x4 o = { (_Float16)v.x, (_Float16)v.y, (_Float16)v.z, (_Float16)v.w };
    ((f16x4*)out)[i] = o;
}

// ------------------------------------------------- x [b][c][n] f32 → Xt [b*196+n][c] f16
__global__ __launch_bounds__(256) void k_transpose_x(const float* __restrict__ x,
                                                     _Float16* __restrict__ Xt) {
    __shared__ __align__(16) _Float16 lds[NPIX][72];
    int t  = threadIdx.x;
    int b  = blockIdx.y, c0 = blockIdx.x * 64;
    const float* xp = x + ((size_t)b * CIN + c0) * NPIX;
    for (int idx = t; idx < 64 * 49; idx += 256) {
        int c = idx / 49, k = idx - c * 49;
        float4 v = *(const float4*)(xp + (size_t)c * NPIX + k * 4);
        int n = k * 4;
        lds[n][c]     = (_Float16)v.x;
        lds[n + 1][c] = (_Float16)v.y;
        lds[n + 2][c] = (_Float16)v.z;
        lds[n + 3][c] = (_Float16)v.w;
    }
    __syncthreads();
    int cs = t & 7, nn = t >> 3;
    for (int n = nn; n < NPIX; n += 32) {
        _Float16* dst = Xt + ((size_t)(b * NPIX + n)) * CIN + c0 + cs * 8;
        *(ulonglong2*)dst = *(const ulonglong2*)&lds[n][cs * 8];
    }
}

// ---------------------------------------------------------------- helpers
__device__ inline void gload16(const _Float16* g, _Float16* l) {
    __builtin_amdgcn_global_load_lds((const __attribute__((address_space(1))) void*)g,
                                     (__attribute__((address_space(3))) void*)l,
                                     16, 0, 0);
}

// ---------------------------------------------------------------- TMxTN 2-barrier GEMM
// R0 proven skeleton generalized over TM/TN (R2/R14-class parameter changes).
// Measured per-dispatch (R14/R15): QKV best at TM=224,TN=256 (53.5us);
// proj best at TM=256,TN=192 (one round, 196 blocks). TM=256 instantiation
// skips the row clamp -> generates R14-identical staging code.
// C[r][o] = sum_c A[r][c]*B[o][c]; A:[12544][768], B:[NTN*TN][768]
// PROJ=false: C f16 [row][2304];  PROJ=true: Cf f32 out[b][col][n]
template<int NTN, int TM, int TN, bool PROJ>
__global__ __launch_bounds__(512, 2) void k_gemm2(const _Float16* __restrict__ A,
                                                  const _Float16* __restrict__ Bm,
                                                  _Float16* __restrict__ Cb,
                                                  float* __restrict__ Cf) {
    constexpr int WRH = TM / 2;        // wave row height: 112 or 128
    constexpr int RF  = WRH / 16;      // row fragments per wave: 7 or 8
    constexpr int WCW = TN / 4;        // wave col width: 64 or 48
    constexpr int CF  = WCW / 16;      // col fragments per wave: 4 or 3
    constexpr int GB  = TN / 64;       // B stage gloads per tile: 4 or 3
    __shared__ __align__(16) _Float16 As[2][256 * 64];   // 64 KiB (256-row sweep)
    __shared__ __align__(16) _Float16 Bs[2][TN * 64];    // 64 or 48 KiB
    int tid = threadIdx.x;
    int w = tid >> 6, lane = tid & 63;

    // T1: bijective XCD swizzle (handles nwg%8 != 0)
    int nwg = gridDim.x;
    int orig = blockIdx.x;
    int q = nwg >> 3, r = nwg & 7;
    int xcd = orig & 7, within = orig >> 3;
    int wg = (xcd < r ? xcd * (q + 1) : r * (q + 1) + (xcd - r) * q) + within;
    int bm = wg / NTN, bn = wg - bm * NTN;
    int m0 = bm * TM, n0 = bn * TN;

    int wr = w >> 2, wc = w & 3;          // 2 x 4 wave grid; wave tile WRH x WCW
    int r16 = lane & 15, q4 = lane >> 4;

    // staging (T2: inverse-swizzled global source; linear LDS dest)
    int sr8  = (w << 3) + (lane >> 3);                    // 0..63
    int swz8 = ((lane & 7) ^ (lane >> 3)) << 3;
    const _Float16* Ag = A  + (size_t)(m0 + sr8) * CIN + swz8;
    const _Float16* Bg = Bm + (size_t)(n0 + sr8) * CIN + swz8;

    auto stageA = [&](int buf, int kt) {
        _Float16* l0 = As[buf] + (w << 9);
        if constexpr (TM == 256) {
            const _Float16* g = Ag + kt * 64;
            gload16(g,             l0);
            gload16(g +  64 * CIN, l0 + 4096);
            gload16(g + 128 * CIN, l0 + 8192);
            gload16(g + 192 * CIN, l0 + 12288);
        } else {
#pragma unroll
            for (int s = 0; s < 4; s++) {
                int row = m0 + sr8 + s * 64;
                if (row > ROWS - 1) row = ROWS - 1;   // clamp: lands in LDS rows >= TM, never read
                gload16(A + (size_t)row * CIN + swz8 + kt * 64, l0 + s * 4096);
            }
        }
    };
    auto stageB = [&](int buf, int kt) {
        const _Float16* g = Bg + kt * 64;
        _Float16* l0 = Bs[buf] + (w << 9);
        gload16(g,             l0);
        gload16(g +  64 * CIN, l0 + 4096);
        gload16(g + 128 * CIN, l0 + 8192);
        if constexpr (GB == 4) gload16(g + 192 * CIN, l0 + 12288);
    };

    // counted-vmcnt invariant: outstanding at tile end = (4+GB) loads of t+2;
    // waiting (4+GB) drains tile t+1. In-order VMEM queue.
#define VM_WAIT_N() do { if constexpr (GB == 4) { asm volatile("s_waitcnt vmcnt(8)" ::: "memory"); } \
                         else                   { asm volatile("s_waitcnt vmcnt(7)" ::: "memory"); } } while (0)

    int cS0 = ((q4)     ^ (r16 & 7)) << 3;
    int cS1 = ((q4 + 4) ^ (r16 & 7)) << 3;

    f32x4 acc[RF][CF];
#pragma unroll
    for (int i = 0; i < RF; i++)
#pragma unroll
        for (int j = 0; j < CF; j++) acc[i][j] = (f32x4){0.f, 0.f, 0.f, 0.f};

    // prologue
    stageA(0, 0); stageB(0, 0);
    stageA(1, 1); stageB(1, 1);
    VM_WAIT_N();
    __builtin_amdgcn_sched_barrier(0);
    __builtin_amdgcn_s_barrier();

#pragma unroll 2
    for (int t = 0; t < NKT; ++t) {
        int bt = t & 1;
        const _Float16* Ab = As[bt] + (wr * WRH + r16) * 64;
        const _Float16* Bb = Bs[bt] + (wc * WCW + r16) * 64;
        bool pre = (t + 2 < NKT);

        // read all fragments for this K-tile (2*RF A + 2*CF B ds_read_b128)
        f16x8 a[RF][2], bb[CF][2];
#pragma unroll
        for (int i = 0; i < RF; i++) {
            a[i][0] = *(const f16x8*)(Ab + (i << 10) + cS0);
            a[i][1] = *(const f16x8*)(Ab + (i << 10) + cS1);
        }
#pragma unroll
        for (int g = 0; g < CF; g++) {
            bb[g][0] = *(const f16x8*)(Bb + (g << 10) + cS0);
            bb[g][1] = *(const f16x8*)(Bb + (g << 10) + cS1);
        }

        // MFMA burst 1: col fragments 0,1
        __builtin_amdgcn_s_setprio(1);
#pragma unroll
        for (int i = 0; i < RF; i++)
#pragma unroll
            for (int g = 0; g < 2; g++) {
                acc[i][g] = MFMA16(a[i][0], bb[g][0], acc[i][g], 0, 0, 0);
                acc[i][g] = MFMA16(a[i][1], bb[g][1], acc[i][g], 0, 0, 0);
            }
        __builtin_amdgcn_s_setprio(0);

        // all reads of buffer bt complete for every wave at this barrier
        asm volatile("s_waitcnt lgkmcnt(0)" ::: "memory");
        __builtin_amdgcn_sched_barrier(0);
        __builtin_amdgcn_s_barrier();

        // stage tile t+2 into the buffer we just finished reading
        if (pre) { stageA(bt, t + 2); stageB(bt, t + 2); }

        // MFMA burst 2: col fragments 2..CF-1
        __builtin_amdgcn_s_setprio(1);
#pragma unroll
        for (int i = 0; i < RF; i++)
#pragma unroll
            for (int g = 2; g < CF; g++) {
                acc[i][g] = MFMA16(a[i][0], bb[g][0], acc[i][g], 0, 0, 0);
                acc[i][g] = MFMA16(a[i][1], bb[g][1], acc[i][g], 0, 0, 0);
            }
        __builtin_amdgcn_s_setprio(0);

        // tile t+1 must be resident before next iteration's reads
        if (pre) { VM_WAIT_N(); }
        else     { asm volatile("s_waitcnt vmcnt(0)" ::: "memory"); }
        __builtin_amdgcn_sched_barrier(0);
        __builtin_amdgcn_s_barrier();
    }
#undef VM_WAIT_N

    if (!PROJ) {
#pragma unroll
        for (int i = 0; i < RF; i++)
#pragma unroll
            for (int rr = 0; rr < 4; rr++) {
                int row = m0 + wr * WRH + i * 16 + q4 * 4 + rr;
                _Float16* cp = Cb + (size_t)row * QKV_OC + n0 + wc * WCW + r16;
#pragma unroll
                for (int ct = 0; ct < CF; ct++)
                    cp[ct * 16] = (_Float16)acc[i][ct][rr];
            }
    } else {
#pragma unroll
        for (int i = 0; i < RF; i++) {
            int row = m0 + wr * WRH + i * 16 + q4 * 4;     // multiple of 4
            int b = row / NPIX;
            int n = row - b * NPIX;                         // 196%4==0: no straddle
#pragma unroll
            for (int ct = 0; ct < CF; ct++) {
                int col = n0 + wc * WCW + ct * 16 + r16;
                f32x4 v = acc[i][ct];
                float4 o; o.x = v[0]; o.y = v[1]; o.z = v[2]; o.w = v[3];
                *(float4*)(Cf + ((size_t)b * CIN + col) * NPIX + n) = o;
            }
        }
    }
}

// ---------------------------------------------------------------- fused attention
// R9 BEST-VERIFIED VERSION (verbatim; 133.8-134.0us across three runs).
// 832 threads = 13 waves per (b,h) block: one q-tile per wave (serial depth 1),
// 3.25 waves/SIMD. LDS 144128 B, 1 block/CU, grid 768 = 3 rounds.
__global__ __launch_bounds__(832) void k_attn(const _Float16* __restrict__ qkv,
                                              _Float16* __restrict__ Ot) {
    __shared__ __align__(16) _Float16 Kl[208 * 64];
    __shared__ __align__(16) _Float16 Vt[64][216];
    __shared__ __align__(16) _Float16 Pl[13][16][216];
    int tid = threadIdx.x, wave = tid >> 6, lane = tid & 63;
    int bh = blockIdx.x;
    int b = bh / NH, h = bh - b * NH;
    const _Float16* base  = qkv + (size_t)b * NPIX * QKV_OC + h * DH;  // Q
    const _Float16* kb    = base + CIN;                                 // K
    const _Float16* vbase = base + 2 * CIN;                             // V

    {
        int c8 = lane & 7;
#pragma unroll
        for (int rr = 0; rr < 2; ++rr) {
            int grp = wave + rr * 13;                       // 0..25 exactly
            int row = grp * 8 + (lane >> 3);
            const _Float16* src = kb + (size_t)row * QKV_OC + ((c8 ^ (row & 7)) << 3);
            gload16(src, Kl + row * 64 + (c8 << 3));
        }
    }
    for (int task = tid; task < 208 * 8; task += 832) {    // 2 iterations exactly
        int m = task >> 3, dc = (task & 7) * 8;
        f16x8 v = *(const f16x8*)(vbase + (size_t)m * QKV_OC + dc);
#pragma unroll
        for (int j = 0; j < 8; j++) Vt[dc + j][m] = v[j];
    }
    __syncthreads();

    int r16 = lane & 15, q4 = lane >> 4, r7 = r16 & 7;
    int kc0 = ((q4)     ^ r7) << 3;
    int kc1 = ((q4 + 4) ^ r7) << 3;
    const float s2 = 0.125f;

    {
        int nt = wave;                                     // one q-tile per wave
        f16x8 aq0 = *(const f16x8*)(base + (size_t)(nt * 16 + r16) * QKV_OC + q4 * 8);
        f16x8 aq1 = *(const f16x8*)(base + (size_t)(nt * 16 + r16) * QKV_OC + 32 + q4 * 8);
        f32x4 L[13];
#pragma unroll
        for (int mt = 0; mt < 13; ++mt) {
            const _Float16* kr = Kl + (mt * 16 + r16) * 64;
            f16x8 bk0 = *(const f16x8*)(kr + kc0);
            f16x8 bk1 = *(const f16x8*)(kr + kc1);
            f32x4 s = {0.f, 0.f, 0.f, 0.f};
            s = MFMA16(aq0, bk0, s, 0, 0, 0);
            s = MFMA16(aq1, bk1, s, 0, 0, 0);
            L[mt] = s;
        }
        float mx[4] = {-1e30f, -1e30f, -1e30f, -1e30f};
#pragma unroll
        for (int mt = 0; mt < 13; ++mt)
#pragma unroll
            for (int r = 0; r < 4; ++r) {
                float lv = L[mt][r] * s2;
                if (mt == 12 && r16 >= 4) lv = -1e30f;   // mask m >= 196
                L[mt][r] = lv;
                mx[r] = fmaxf(mx[r], lv);
            }
#pragma unroll
        for (int r = 0; r < 4; ++r)
            for (int off = 1; off < 16; off <<= 1)
                mx[r] = fmaxf(mx[r], __shfl_xor(mx[r], off));
        float sm[4] = {0.f, 0.f, 0.f, 0.f};
#pragma unroll
        for (int mt = 0; mt < 13; ++mt)
#pragma unroll
            for (int r = 0; r < 4; ++r) {
                float p = exp2f((L[mt][r] - mx[r]) * 1.44269504f);
                sm[r] += p;
                Pl[wave][q4 * 4 + r][mt * 16 + r16] = (_Float16)p;
            }
#pragma unroll
        for (int r = 0; r < 4; ++r)
            for (int off = 1; off < 16; off <<= 1)
                sm[r] += __shfl_xor(sm[r], off);

        f32x4 oacc[4];
#pragma unroll
        for (int di = 0; di < 4; ++di) oacc[di] = (f32x4){0.f, 0.f, 0.f, 0.f};
#pragma unroll
        for (int mc = 0; mc < 6; ++mc) {
            f16x8 ap = *(const f16x8*)&Pl[wave][r16][mc * 32 + q4 * 8];
#pragma unroll
            for (int di = 0; di < 4; ++di) {
                f16x8 bv = *(const f16x8*)&Vt[di * 16 + r16][mc * 32 + q4 * 8];
                oacc[di] = MFMA16(ap, bv, oacc[di], 0, 0, 0);
            }
        }
        {
            _Float16 z = (_Float16)0.f;
            f16x8 zz = (f16x8){z, z, z, z, z, z, z, z};
            f16x8 ap = (q4 < 2) ? *(const f16x8*)&Pl[wave][r16][192 + q4 * 8] : zz;
#pragma unroll
            for (int di = 0; di < 4; ++di) {
                f16x8 bv = (q4 < 2) ? *(const f16x8*)&Vt[di * 16 + r16][192 + q4 * 8] : zz;
                oacc[di] = MFMA16(ap, bv, oacc[di], 0, 0, 0);
            }
        }
#pragma unroll
        for (int r = 0; r < 4; ++r) {
            int n = nt * 16 + q4 * 4 + r;
            if (n < NPIX) {
                float rinv = 1.0f / sm[r];
                _Float16* op = Ot + (size_t)(b * NPIX + n) * CIN + h * DH + r16;
#pragma unroll
                for (int di = 0; di < 4; ++di)
                    op[di * 16] = (_Float16)(oacc[di][r] * rinv);
            }
        }
    }
}

// ---------------------------------------------------------------- launch
extern "C" void kernel_launch(void* const* d_in, const int* in_sizes, int n_in,
                              void* d_out, int out_size, void* d_ws, size_t ws_size,
                              hipStream_t stream) {
    const float* x  = (const float*)d_in[0];
    const float* wq = (const float*)d_in[1];
    const float* wp = (const float*)d_in[2];
    float* out = (float*)d_out;
    char* ws = (char*)d_ws;

    _Float16* Xt  = (_Float16*)(ws);
    _Float16* W   = (_Float16*)(ws + 20447232);
    _Float16* qkv = (_Float16*)(ws + 25165824);
    _Float16* Ot  = (_Float16*)(ws + 86507520);
    _Float16* Wq = W;
    _Float16* Wp = W + (size_t)QKV_OC * CIN;

    hipLaunchKernelGGL(k_convert_w, dim3(2304), dim3(256), 0, stream, wq, wp, W);
    hipLaunchKernelGGL(k_transpose_x, dim3(12, 64), dim3(256), 0, stream, x, Xt);
    hipLaunchKernelGGL((k_gemm2<9, 224, 256, false>), dim3(56 * 9), dim3(512), 0, stream,
                       Xt, Wq, qkv, (float*)nullptr);
    hipLaunchKernelGGL(k_attn, dim3(768), dim3(832), 0, stream, qkv, Ot);
    hipLaunchKernelGGL((k_gemm2<4, 256, 192, true>), dim3(49 * 4), dim3(512), 0, stream,
                       Ot, Wp, (_Float16*)nullptr, out);
}

// Round 18
// 131.473 us; speedup vs baseline: 1.0310x; 1.0310x over previous
//
#include <hip/hip_runtime.h>
#include <cstdint>
#include <cstddef>

#define NH     12
#define DH     64
#define CIN    768
#define NPIX   196
#define NB     64
#define ROWS   (NB * NPIX)      // 12544
#define QKV_OC 2304
#define NKT    12               // 768/64

typedef __attribute__((ext_vector_type(8))) _Float16 f16x8;
typedef __attribute__((ext_vector_type(4))) _Float16 f16x4;
typedef __attribute__((ext_vector_type(4))) float    f32x4;

#define MFMA16 __builtin_amdgcn_mfma_f32_16x16x32_f16

// ---------------------------------------------------------------- weights → fp16
__global__ __launch_bounds__(256) void k_convert_w(const float* __restrict__ wq,
                                                   const float* __restrict__ wp,
                                                   _Float16* __restrict__ out) {
    int i = blockIdx.x * 256 + threadIdx.x;
    const int NQ = QKV_OC * CIN / 4;
    const int NT = NQ + (CIN * CIN) / 4;
    if (i >= NT) return;
    float4 v = (i < NQ) ? ((const float4*)wq)[i] : ((const float4*)wp)[i - NQ];
    f16x4 o = { (_Float16)v.x, (_Float16)v.y, (_Float16)v.z, (_Float16)v.w };
    ((f16x4*)out)[i] = o;
}

// ------------------------------------------------- x [b][c][n] f32 → Xt [b*196+n][c] f16
__global__ __launch_bounds__(256) void k_transpose_x(const float* __restrict__ x,
                                                     _Float16* __restrict__ Xt) {
    __shared__ __align__(16) _Float16 lds[NPIX][72];
    int t  = threadIdx.x;
    int b  = blockIdx.y, c0 = blockIdx.x * 64;
    const float* xp = x + ((size_t)b * CIN + c0) * NPIX;
    for (int idx = t; idx < 64 * 49; idx += 256) {
        int c = idx / 49, k = idx - c * 49;
        float4 v = *(const float4*)(xp + (size_t)c * NPIX + k * 4);
        int n = k * 4;
        lds[n][c]     = (_Float16)v.x;
        lds[n + 1][c] = (_Float16)v.y;
        lds[n + 2][c] = (_Float16)v.z;
        lds[n + 3][c] = (_Float16)v.w;
    }
    __syncthreads();
    int cs = t & 7, nn = t >> 3;
    for (int n = nn; n < NPIX; n += 32) {
        _Float16* dst = Xt + ((size_t)(b * NPIX + n)) * CIN + c0 + cs * 8;
        *(ulonglong2*)dst = *(const ulonglong2*)&lds[n][cs * 8];
    }
}

// ---------------------------------------------------------------- helpers
__device__ inline void gload16(const _Float16* g, _Float16* l) {
    __builtin_amdgcn_global_load_lds((const __attribute__((address_space(1))) void*)g,
                                     (__attribute__((address_space(3))) void*)l,
                                     16, 0, 0);
}

// ---------------------------------------------------------------- 256xTN 2-barrier GEMM
// R14 BEST-VERIFIED VERSION (131.0us e2e). TM fixed at 256 — R15/R16 measured
// that TM=224 speeds its own dispatch (55->53) but costs ~4-6us e2e (downstream
// qkv L2 distribution for the latency-bound attn + co-compiled-instantiation
// codegen effects). TN=256 generates the frozen R0 QKV code; TN=192 gives proj
// one round (49x4=196 blocks) at 0.9x block work.
// C[r][o] = sum_c A[r][c]*B[o][c]; A:[12544][768], B:[NTN*TN][768]
// PROJ=false: C f16 [row][2304];  PROJ=true: Cf f32 out[b][col][n]
template<int NTN, int TN, bool PROJ>
__global__ __launch_bounds__(512, 2) void k_gemm2(const _Float16* __restrict__ A,
                                                  const _Float16* __restrict__ Bm,
                                                  _Float16* __restrict__ Cb,
                                                  float* __restrict__ Cf) {
    constexpr int WCW = TN / 4;        // wave col-tile width: 64 or 48
    constexpr int CF  = WCW / 16;      // col fragments per wave: 4 or 3
    constexpr int GB  = TN / 64;       // B stage gloads per tile: 4 or 3
    __shared__ __align__(16) _Float16 As[2][256 * 64];   // 64 KiB
    __shared__ __align__(16) _Float16 Bs[2][TN * 64];    // 64 or 48 KiB
    int tid = threadIdx.x;
    int w = tid >> 6, lane = tid & 63;

    // T1: bijective XCD swizzle (handles nwg%8 != 0)
    int nwg = gridDim.x;
    int orig = blockIdx.x;
    int q = nwg >> 3, r = nwg & 7;
    int xcd = orig & 7, within = orig >> 3;
    int wg = (xcd < r ? xcd * (q + 1) : r * (q + 1) + (xcd - r) * q) + within;
    int bm = wg / NTN, bn = wg - bm * NTN;
    int m0 = bm * 256, n0 = bn * TN;

    int wr = w >> 2, wc = w & 3;          // 2 x 4 wave grid; wave tile 128 x WCW
    int r16 = lane & 15, q4 = lane >> 4;

    // staging (T2: inverse-swizzled global source; linear LDS dest)
    int sr8  = (w << 3) + (lane >> 3);                    // 0..63
    int swz8 = ((lane & 7) ^ (lane >> 3)) << 3;
    const _Float16* Ag = A  + (size_t)(m0 + sr8) * CIN + swz8;
    const _Float16* Bg = Bm + (size_t)(n0 + sr8) * CIN + swz8;

    auto stageA = [&](int buf, int kt) {
        const _Float16* g = Ag + kt * 64;
        _Float16* l0 = As[buf] + (w << 9);
        gload16(g,             l0);
        gload16(g +  64 * CIN, l0 + 4096);
        gload16(g + 128 * CIN, l0 + 8192);
        gload16(g + 192 * CIN, l0 + 12288);
    };
    auto stageB = [&](int buf, int kt) {
        const _Float16* g = Bg + kt * 64;
        _Float16* l0 = Bs[buf] + (w << 9);
        gload16(g,             l0);
        gload16(g +  64 * CIN, l0 + 4096);
        gload16(g + 128 * CIN, l0 + 8192);
        if constexpr (GB == 4) gload16(g + 192 * CIN, l0 + 12288);
    };

    // counted-vmcnt invariant: outstanding at tile end = (4+GB) loads of t+2;
    // waiting (4+GB) drains tile t+1. In-order VMEM queue (m135).
#define VM_WAIT_N() do { if constexpr (TN == 256) { asm volatile("s_waitcnt vmcnt(8)" ::: "memory"); } \
                         else                     { asm volatile("s_waitcnt vmcnt(7)" ::: "memory"); } } while (0)

    int cS0 = ((q4)     ^ (r16 & 7)) << 3;
    int cS1 = ((q4 + 4) ^ (r16 & 7)) << 3;

    f32x4 acc[8][CF];
#pragma unroll
    for (int i = 0; i < 8; i++)
#pragma unroll
        for (int j = 0; j < CF; j++) acc[i][j] = (f32x4){0.f, 0.f, 0.f, 0.f};

    // prologue
    stageA(0, 0); stageB(0, 0);
    stageA(1, 1); stageB(1, 1);
    VM_WAIT_N();
    __builtin_amdgcn_sched_barrier(0);
    __builtin_amdgcn_s_barrier();

#pragma unroll 2
    for (int t = 0; t < NKT; ++t) {
        int bt = t & 1;
        const _Float16* Ab = As[bt] + ((wr << 7) + r16) * 64;
        const _Float16* Bb = Bs[bt] + (wc * WCW + r16) * 64;
        bool pre = (t + 2 < NKT);

        // read all fragments for this K-tile (16 A + 2*CF B ds_read_b128)
        f16x8 a0[4][2], a1[4][2], bb[CF][2];
#pragma unroll
        for (int i = 0; i < 4; i++) {
            a0[i][0] = *(const f16x8*)(Ab + (i << 10) + cS0);
            a0[i][1] = *(const f16x8*)(Ab + (i << 10) + cS1);
            a1[i][0] = *(const f16x8*)(Ab + 4096 + (i << 10) + cS0);
            a1[i][1] = *(const f16x8*)(Ab + 4096 + (i << 10) + cS1);
        }
#pragma unroll
        for (int g = 0; g < CF; g++) {
            bb[g][0] = *(const f16x8*)(Bb + (g << 10) + cS0);
            bb[g][1] = *(const f16x8*)(Bb + (g << 10) + cS1);
        }

        // MFMA burst 1: col fragments 0,1
        __builtin_amdgcn_s_setprio(1);
#pragma unroll
        for (int i = 0; i < 4; i++)
#pragma unroll
            for (int g = 0; g < 2; g++) {
                acc[i][g]     = MFMA16(a0[i][0], bb[g][0], acc[i][g],     0, 0, 0);
                acc[i][g]     = MFMA16(a0[i][1], bb[g][1], acc[i][g],     0, 0, 0);
                acc[4 + i][g] = MFMA16(a1[i][0], bb[g][0], acc[4 + i][g], 0, 0, 0);
                acc[4 + i][g] = MFMA16(a1[i][1], bb[g][1], acc[4 + i][g], 0, 0, 0);
            }
        __builtin_amdgcn_s_setprio(0);

        // all reads of buffer bt complete for every wave at this barrier
        asm volatile("s_waitcnt lgkmcnt(0)" ::: "memory");
        __builtin_amdgcn_sched_barrier(0);
        __builtin_amdgcn_s_barrier();

        // stage tile t+2 into the buffer we just finished reading
        if (pre) { stageA(bt, t + 2); stageB(bt, t + 2); }

        // MFMA burst 2: col fragments 2..CF-1
        __builtin_amdgcn_s_setprio(1);
#pragma unroll
        for (int i = 0; i < 4; i++)
#pragma unroll
            for (int g = 2; g < CF; g++) {
                acc[i][g]     = MFMA16(a0[i][0], bb[g][0], acc[i][g],     0, 0, 0);
                acc[i][g]     = MFMA16(a0[i][1], bb[g][1], acc[i][g],     0, 0, 0);
                acc[4 + i][g] = MFMA16(a1[i][0], bb[g][0], acc[4 + i][g], 0, 0, 0);
                acc[4 + i][g] = MFMA16(a1[i][1], bb[g][1], acc[4 + i][g], 0, 0, 0);
            }
        __builtin_amdgcn_s_setprio(0);

        // tile t+1 must be resident before next iteration's reads
        if (pre) { VM_WAIT_N(); }
        else     { asm volatile("s_waitcnt vmcnt(0)" ::: "memory"); }
        __builtin_amdgcn_sched_barrier(0);
        __builtin_amdgcn_s_barrier();
    }
#undef VM_WAIT_N

    if (!PROJ) {
#pragma unroll
        for (int hh = 0; hh < 2; hh++)
#pragma unroll
            for (int i = 0; i < 4; i++)
#pragma unroll
                for (int rr = 0; rr < 4; rr++) {
                    int row = m0 + (wr << 7) + hh * 64 + i * 16 + q4 * 4 + rr;
                    _Float16* cp = Cb + (size_t)row * QKV_OC + n0 + wc * WCW + r16;
#pragma unroll
                    for (int ct = 0; ct < CF; ct++)
                        cp[ct * 16] = (_Float16)acc[hh * 4 + i][ct][rr];
                }
    } else {
#pragma unroll
        for (int hh = 0; hh < 2; hh++)
#pragma unroll
            for (int i = 0; i < 4; i++) {
                int row = m0 + (wr << 7) + hh * 64 + i * 16 + q4 * 4;  // mult of 4
                int b = row / NPIX;
                int n = row - b * NPIX;                                 // 196%4==0: no straddle
#pragma unroll
                for (int ct = 0; ct < CF; ct++) {
                    int col = n0 + wc * WCW + ct * 16 + r16;
                    f32x4 a = acc[hh * 4 + i][ct];
                    float4 o; o.x = a[0]; o.y = a[1]; o.z = a[2]; o.w = a[3];
                    *(float4*)(Cf + ((size_t)b * CIN + col) * NPIX + n) = o;
                }
            }
    }
}

// ---------------------------------------------------------------- fused attention
// R9 BEST-VERIFIED VERSION (verbatim; 133.8-134.0us across three runs).
// 832 threads = 13 waves per (b,h) block: one q-tile per wave (serial depth 1),
// 3.25 waves/SIMD. LDS 144128 B, 1 block/CU, grid 768 = 3 rounds.
__global__ __launch_bounds__(832) void k_attn(const _Float16* __restrict__ qkv,
                                              _Float16* __restrict__ Ot) {
    __shared__ __align__(16) _Float16 Kl[208 * 64];
    __shared__ __align__(16) _Float16 Vt[64][216];
    __shared__ __align__(16) _Float16 Pl[13][16][216];
    int tid = threadIdx.x, wave = tid >> 6, lane = tid & 63;
    int bh = blockIdx.x;
    int b = bh / NH, h = bh - b * NH;
    const _Float16* base  = qkv + (size_t)b * NPIX * QKV_OC + h * DH;  // Q
    const _Float16* kb    = base + CIN;                                 // K
    const _Float16* vbase = base + 2 * CIN;                             // V

    {
        int c8 = lane & 7;
#pragma unroll
        for (int rr = 0; rr < 2; ++rr) {
            int grp = wave + rr * 13;                       // 0..25 exactly
            int row = grp * 8 + (lane >> 3);
            const _Float16* src = kb + (size_t)row * QKV_OC + ((c8 ^ (row & 7)) << 3);
            gload16(src, Kl + row * 64 + (c8 << 3));
        }
    }
    for (int task = tid; task < 208 * 8; task += 832) {    // 2 iterations exactly
        int m = task >> 3, dc = (task & 7) * 8;
        f16x8 v = *(const f16x8*)(vbase + (size_t)m * QKV_OC + dc);
#pragma unroll
        for (int j = 0; j < 8; j++) Vt[dc + j][m] = v[j];
    }
    __syncthreads();

    int r16 = lane & 15, q4 = lane >> 4, r7 = r16 & 7;
    int kc0 = ((q4)     ^ r7) << 3;
    int kc1 = ((q4 + 4) ^ r7) << 3;
    const float s2 = 0.125f;

    {
        int nt = wave;                                     // one q-tile per wave
        f16x8 aq0 = *(const f16x8*)(base + (size_t)(nt * 16 + r16) * QKV_OC + q4 * 8);
        f16x8 aq1 = *(const f16x8*)(base + (size_t)(nt * 16 + r16) * QKV_OC + 32 + q4 * 8);
        f32x4 L[13];
#pragma unroll
        for (int mt = 0; mt < 13; ++mt) {
            const _Float16* kr = Kl + (mt * 16 + r16) * 64;
            f16x8 bk0 = *(const f16x8*)(kr + kc0);
            f16x8 bk1 = *(const f16x8*)(kr + kc1);
            f32x4 s = {0.f, 0.f, 0.f, 0.f};
            s = MFMA16(aq0, bk0, s, 0, 0, 0);
            s = MFMA16(aq1, bk1, s, 0, 0, 0);
            L[mt] = s;
        }
        float mx[4] = {-1e30f, -1e30f, -1e30f, -1e30f};
#pragma unroll
        for (int mt = 0; mt < 13; ++mt)
#pragma unroll
            for (int r = 0; r < 4; ++r) {
                float lv = L[mt][r] * s2;
                if (mt == 12 && r16 >= 4) lv = -1e30f;   // mask m >= 196
                L[mt][r] = lv;
                mx[r] = fmaxf(mx[r], lv);
            }
#pragma unroll
        for (int r = 0; r < 4; ++r)
            for (int off = 1; off < 16; off <<= 1)
                mx[r] = fmaxf(mx[r], __shfl_xor(mx[r], off));
        float sm[4] = {0.f, 0.f, 0.f, 0.f};
#pragma unroll
        for (int mt = 0; mt < 13; ++mt)
#pragma unroll
            for (int r = 0; r < 4; ++r) {
                float p = exp2f((L[mt][r] - mx[r]) * 1.44269504f);
                sm[r] += p;
                Pl[wave][q4 * 4 + r][mt * 16 + r16] = (_Float16)p;
            }
#pragma unroll
        for (int r = 0; r < 4; ++r)
            for (int off = 1; off < 16; off <<= 1)
                sm[r] += __shfl_xor(sm[r], off);

        f32x4 oacc[4];
#pragma unroll
        for (int di = 0; di < 4; ++di) oacc[di] = (f32x4){0.f, 0.f, 0.f, 0.f};
#pragma unroll
        for (int mc = 0; mc < 6; ++mc) {
            f16x8 ap = *(const f16x8*)&Pl[wave][r16][mc * 32 + q4 * 8];
#pragma unroll
            for (int di = 0; di < 4; ++di) {
                f16x8 bv = *(const f16x8*)&Vt[di * 16 + r16][mc * 32 + q4 * 8];
                oacc[di] = MFMA16(ap, bv, oacc[di], 0, 0, 0);
            }
        }
        {
            _Float16 z = (_Float16)0.f;
            f16x8 zz = (f16x8){z, z, z, z, z, z, z, z};
            f16x8 ap = (q4 < 2) ? *(const f16x8*)&Pl[wave][r16][192 + q4 * 8] : zz;
#pragma unroll
            for (int di = 0; di < 4; ++di) {
                f16x8 bv = (q4 < 2) ? *(const f16x8*)&Vt[di * 16 + r16][192 + q4 * 8] : zz;
                oacc[di] = MFMA16(ap, bv, oacc[di], 0, 0, 0);
            }
        }
#pragma unroll
        for (int r = 0; r < 4; ++r) {
            int n = nt * 16 + q4 * 4 + r;
            if (n < NPIX) {
                float rinv = 1.0f / sm[r];
                _Float16* op = Ot + (size_t)(b * NPIX + n) * CIN + h * DH + r16;
#pragma unroll
                for (int di = 0; di < 4; ++di)
                    op[di * 16] = (_Float16)(oacc[di][r] * rinv);
            }
        }
    }
}

// ---------------------------------------------------------------- launch
extern "C" void kernel_launch(void* const* d_in, const int* in_sizes, int n_in,
                              void* d_out, int out_size, void* d_ws, size_t ws_size,
                              hipStream_t stream) {
    const float* x  = (const float*)d_in[0];
    const float* wq = (const float*)d_in[1];
    const float* wp = (const float*)d_in[2];
    float* out = (float*)d_out;
    char* ws = (char*)d_ws;

    _Float16* Xt  = (_Float16*)(ws);
    _Float16* W   = (_Float16*)(ws + 20447232);
    _Float16* qkv = (_Float16*)(ws + 25165824);
    _Float16* Ot  = (_Float16*)(ws + 86507520);
    _Float16* Wq = W;
    _Float16* Wp = W + (size_t)QKV_OC * CIN;

    hipLaunchKernelGGL(k_convert_w, dim3(2304), dim3(256), 0, stream, wq, wp, W);
    hipLaunchKernelGGL(k_transpose_x, dim3(12, 64), dim3(256), 0, stream, x, Xt);
    hipLaunchKernelGGL((k_gemm2<9, 256, false>), dim3(49 * 9), dim3(512), 0, stream,
                       Xt, Wq, qkv, (float*)nullptr);
    hipLaunchKernelGGL(k_attn, dim3(768), dim3(832), 0, stream, qkv, Ot);
    hipLaunchKernelGGL((k_gemm2<4, 192, true>), dim3(49 * 4), dim3(512), 0, stream,
                       Ot, Wp, (_Float16*)nullptr, out);
}

// Round 19
// 131.264 us; speedup vs baseline: 1.0326x; 1.0016x over previous
//
#include <hip/hip_runtime.h>
#include <cstdint>
#include <cstddef>

#define NH     12
#define DH     64
#define CIN    768
#define NPIX   196
#define NB     64
#define ROWS   (NB * NPIX)      // 12544
#define QKV_OC 2304
#define NKT    12               // 768/64

typedef __attribute__((ext_vector_type(8))) _Float16 f16x8;
typedef __attribute__((ext_vector_type(4))) _Float16 f16x4;
typedef __attribute__((ext_vector_type(4))) float    f32x4;

#define MFMA16 __builtin_amdgcn_mfma_f32_16x16x32_f16

// ---------------------------------------------------------------- weights → fp16
__global__ __launch_bounds__(256) void k_convert_w(const float* __restrict__ wq,
                                                   const float* __restrict__ wp,
                                                   _Float16* __restrict__ out) {
    int i = blockIdx.x * 256 + threadIdx.x;
    const int NQ = QKV_OC * CIN / 4;
    const int NT = NQ + (CIN * CIN) / 4;
    if (i >= NT) return;
    float4 v = (i < NQ) ? ((const float4*)wq)[i] : ((const float4*)wp)[i - NQ];
    f16x4 o = { (_Float16)v.x, (_Float16)v.y, (_Float16)v.z, (_Float16)v.w };
    ((f16x4*)out)[i] = o;
}

// ------------------------------------------------- x [b][c][n] f32 → Xt [b*196+n][c] f16
__global__ __launch_bounds__(256) void k_transpose_x(const float* __restrict__ x,
                                                     _Float16* __restrict__ Xt) {
    __shared__ __align__(16) _Float16 lds[NPIX][72];
    int t  = threadIdx.x;
    int b  = blockIdx.y, c0 = blockIdx.x * 64;
    const float* xp = x + ((size_t)b * CIN + c0) * NPIX;
    for (int idx = t; idx < 64 * 49; idx += 256) {
        int c = idx / 49, k = idx - c * 49;
        float4 v = *(const float4*)(xp + (size_t)c * NPIX + k * 4);
        int n = k * 4;
        lds[n][c]     = (_Float16)v.x;
        lds[n + 1][c] = (_Float16)v.y;
        lds[n + 2][c] = (_Float16)v.z;
        lds[n + 3][c] = (_Float16)v.w;
    }
    __syncthreads();
    int cs = t & 7, nn = t >> 3;
    for (int n = nn; n < NPIX; n += 32) {
        _Float16* dst = Xt + ((size_t)(b * NPIX + n)) * CIN + c0 + cs * 8;
        *(ulonglong2*)dst = *(const ulonglong2*)&lds[n][cs * 8];
    }
}

// ---------------------------------------------------------------- helpers
__device__ inline void gload16(const _Float16* g, _Float16* l) {
    __builtin_amdgcn_global_load_lds((const __attribute__((address_space(1))) void*)g,
                                     (__attribute__((address_space(3))) void*)l,
                                     16, 0, 0);
}

// ---------------------------------------------------------------- 256xTN 2-barrier GEMM
// R14 BEST-VERIFIED VERSION (131.0us e2e; reproduced 131.5 R18). TM fixed at 256 —
// R15/R16 measured that TM=224 speeds its own dispatch (55->53) but costs ~4-6us
// e2e (downstream qkv L2 distribution for the latency-bound attn + co-compiled-
// instantiation codegen effects). TN=256 generates the frozen R0 QKV code;
// TN=192 gives proj one round (49x4=196 blocks) at 0.9x block work.
// C[r][o] = sum_c A[r][c]*B[o][c]; A:[12544][768], B:[NTN*TN][768]
// PROJ=false: C f16 [row][2304];  PROJ=true: Cf f32 out[b][col][n]
template<int NTN, int TN, bool PROJ>
__global__ __launch_bounds__(512, 2) void k_gemm2(const _Float16* __restrict__ A,
                                                  const _Float16* __restrict__ Bm,
                                                  _Float16* __restrict__ Cb,
                                                  float* __restrict__ Cf) {
    constexpr int WCW = TN / 4;        // wave col-tile width: 64 or 48
    constexpr int CF  = WCW / 16;      // col fragments per wave: 4 or 3
    constexpr int GB  = TN / 64;       // B stage gloads per tile: 4 or 3
    __shared__ __align__(16) _Float16 As[2][256 * 64];   // 64 KiB
    __shared__ __align__(16) _Float16 Bs[2][TN * 64];    // 64 or 48 KiB
    int tid = threadIdx.x;
    int w = tid >> 6, lane = tid & 63;

    // T1: bijective XCD swizzle (handles nwg%8 != 0)
    int nwg = gridDim.x;
    int orig = blockIdx.x;
    int q = nwg >> 3, r = nwg & 7;
    int xcd = orig & 7, within = orig >> 3;
    int wg = (xcd < r ? xcd * (q + 1) : r * (q + 1) + (xcd - r) * q) + within;
    int bm = wg / NTN, bn = wg - bm * NTN;
    int m0 = bm * 256, n0 = bn * TN;

    int wr = w >> 2, wc = w & 3;          // 2 x 4 wave grid; wave tile 128 x WCW
    int r16 = lane & 15, q4 = lane >> 4;

    // staging (T2: inverse-swizzled global source; linear LDS dest)
    int sr8  = (w << 3) + (lane >> 3);                    // 0..63
    int swz8 = ((lane & 7) ^ (lane >> 3)) << 3;
    const _Float16* Ag = A  + (size_t)(m0 + sr8) * CIN + swz8;
    const _Float16* Bg = Bm + (size_t)(n0 + sr8) * CIN + swz8;

    auto stageA = [&](int buf, int kt) {
        const _Float16* g = Ag + kt * 64;
        _Float16* l0 = As[buf] + (w << 9);
        gload16(g,             l0);
        gload16(g +  64 * CIN, l0 + 4096);
        gload16(g + 128 * CIN, l0 + 8192);
        gload16(g + 192 * CIN, l0 + 12288);
    };
    auto stageB = [&](int buf, int kt) {
        const _Float16* g = Bg + kt * 64;
        _Float16* l0 = Bs[buf] + (w << 9);
        gload16(g,             l0);
        gload16(g +  64 * CIN, l0 + 4096);
        gload16(g + 128 * CIN, l0 + 8192);
        if constexpr (GB == 4) gload16(g + 192 * CIN, l0 + 12288);
    };

    // counted-vmcnt invariant: outstanding at tile end = (4+GB) loads of t+2;
    // waiting (4+GB) drains tile t+1. In-order VMEM queue (m135).
#define VM_WAIT_N() do { if constexpr (TN == 256) { asm volatile("s_waitcnt vmcnt(8)" ::: "memory"); } \
                         else                     { asm volatile("s_waitcnt vmcnt(7)" ::: "memory"); } } while (0)

    int cS0 = ((q4)     ^ (r16 & 7)) << 3;
    int cS1 = ((q4 + 4) ^ (r16 & 7)) << 3;

    f32x4 acc[8][CF];
#pragma unroll
    for (int i = 0; i < 8; i++)
#pragma unroll
        for (int j = 0; j < CF; j++) acc[i][j] = (f32x4){0.f, 0.f, 0.f, 0.f};

    // prologue
    stageA(0, 0); stageB(0, 0);
    stageA(1, 1); stageB(1, 1);
    VM_WAIT_N();
    __builtin_amdgcn_sched_barrier(0);
    __builtin_amdgcn_s_barrier();

#pragma unroll 2
    for (int t = 0; t < NKT; ++t) {
        int bt = t & 1;
        const _Float16* Ab = As[bt] + ((wr << 7) + r16) * 64;
        const _Float16* Bb = Bs[bt] + (wc * WCW + r16) * 64;
        bool pre = (t + 2 < NKT);

        // read all fragments for this K-tile (16 A + 2*CF B ds_read_b128)
        f16x8 a0[4][2], a1[4][2], bb[CF][2];
#pragma unroll
        for (int i = 0; i < 4; i++) {
            a0[i][0] = *(const f16x8*)(Ab + (i << 10) + cS0);
            a0[i][1] = *(const f16x8*)(Ab + (i << 10) + cS1);
            a1[i][0] = *(const f16x8*)(Ab + 4096 + (i << 10) + cS0);
            a1[i][1] = *(const f16x8*)(Ab + 4096 + (i << 10) + cS1);
        }
#pragma unroll
        for (int g = 0; g < CF; g++) {
            bb[g][0] = *(const f16x8*)(Bb + (g << 10) + cS0);
            bb[g][1] = *(const f16x8*)(Bb + (g << 10) + cS1);
        }

        // MFMA burst 1: col fragments 0,1
        __builtin_amdgcn_s_setprio(1);
#pragma unroll
        for (int i = 0; i < 4; i++)
#pragma unroll
            for (int g = 0; g < 2; g++) {
                acc[i][g]     = MFMA16(a0[i][0], bb[g][0], acc[i][g],     0, 0, 0);
                acc[i][g]     = MFMA16(a0[i][1], bb[g][1], acc[i][g],     0, 0, 0);
                acc[4 + i][g] = MFMA16(a1[i][0], bb[g][0], acc[4 + i][g], 0, 0, 0);
                acc[4 + i][g] = MFMA16(a1[i][1], bb[g][1], acc[4 + i][g], 0, 0, 0);
            }
        __builtin_amdgcn_s_setprio(0);

        // all reads of buffer bt complete for every wave at this barrier
        asm volatile("s_waitcnt lgkmcnt(0)" ::: "memory");
        __builtin_amdgcn_sched_barrier(0);
        __builtin_amdgcn_s_barrier();

        // stage tile t+2 into the buffer we just finished reading
        if (pre) { stageA(bt, t + 2); stageB(bt, t + 2); }

        // MFMA burst 2: col fragments 2..CF-1
        __builtin_amdgcn_s_setprio(1);
#pragma unroll
        for (int i = 0; i < 4; i++)
#pragma unroll
            for (int g = 2; g < CF; g++) {
                acc[i][g]     = MFMA16(a0[i][0], bb[g][0], acc[i][g],     0, 0, 0);
                acc[i][g]     = MFMA16(a0[i][1], bb[g][1], acc[i][g],     0, 0, 0);
                acc[4 + i][g] = MFMA16(a1[i][0], bb[g][0], acc[4 + i][g], 0, 0, 0);
                acc[4 + i][g] = MFMA16(a1[i][1], bb[g][1], acc[4 + i][g], 0, 0, 0);
            }
        __builtin_amdgcn_s_setprio(0);

        // tile t+1 must be resident before next iteration's reads
        if (pre) { VM_WAIT_N(); }
        else     { asm volatile("s_waitcnt vmcnt(0)" ::: "memory"); }
        __builtin_amdgcn_sched_barrier(0);
        __builtin_amdgcn_s_barrier();
    }
#undef VM_WAIT_N

    if (!PROJ) {
#pragma unroll
        for (int hh = 0; hh < 2; hh++)
#pragma unroll
            for (int i = 0; i < 4; i++)
#pragma unroll
                for (int rr = 0; rr < 4; rr++) {
                    int row = m0 + (wr << 7) + hh * 64 + i * 16 + q4 * 4 + rr;
                    _Float16* cp = Cb + (size_t)row * QKV_OC + n0 + wc * WCW + r16;
#pragma unroll
                    for (int ct = 0; ct < CF; ct++)
                        cp[ct * 16] = (_Float16)acc[hh * 4 + i][ct][rr];
                }
    } else {
#pragma unroll
        for (int hh = 0; hh < 2; hh++)
#pragma unroll
            for (int i = 0; i < 4; i++) {
                int row = m0 + (wr << 7) + hh * 64 + i * 16 + q4 * 4;  // mult of 4
                int b = row / NPIX;
                int n = row - b * NPIX;                                 // 196%4==0: no straddle
#pragma unroll
                for (int ct = 0; ct < CF; ct++) {
                    int col = n0 + wc * WCW + ct * 16 + r16;
                    f32x4 a = acc[hh * 4 + i][ct];
                    float4 o; o.x = a[0]; o.y = a[1]; o.z = a[2]; o.w = a[3];
                    *(float4*)(Cf + ((size_t)b * CIN + col) * NPIX + n) = o;
                }
            }
    }
}

// ---------------------------------------------------------------- fused attention
// R9 BEST-VERIFIED VERSION (verbatim; 133.8-134.0us across three runs).
// 832 threads = 13 waves per (b,h) block: one q-tile per wave (serial depth 1),
// 3.25 waves/SIMD. LDS 144128 B, 1 block/CU, grid 768 = 3 rounds.
__global__ __launch_bounds__(832) void k_attn(const _Float16* __restrict__ qkv,
                                              _Float16* __restrict__ Ot) {
    __shared__ __align__(16) _Float16 Kl[208 * 64];
    __shared__ __align__(16) _Float16 Vt[64][216];
    __shared__ __align__(16) _Float16 Pl[13][16][216];
    int tid = threadIdx.x, wave = tid >> 6, lane = tid & 63;
    int bh = blockIdx.x;
    int b = bh / NH, h = bh - b * NH;
    const _Float16* base  = qkv + (size_t)b * NPIX * QKV_OC + h * DH;  // Q
    const _Float16* kb    = base + CIN;                                 // K
    const _Float16* vbase = base + 2 * CIN;                             // V

    {
        int c8 = lane & 7;
#pragma unroll
        for (int rr = 0; rr < 2; ++rr) {
            int grp = wave + rr * 13;                       // 0..25 exactly
            int row = grp * 8 + (lane >> 3);
            const _Float16* src = kb + (size_t)row * QKV_OC + ((c8 ^ (row & 7)) << 3);
            gload16(src, Kl + row * 64 + (c8 << 3));
        }
    }
    for (int task = tid; task < 208 * 8; task += 832) {    // 2 iterations exactly
        int m = task >> 3, dc = (task & 7) * 8;
        f16x8 v = *(const f16x8*)(vbase + (size_t)m * QKV_OC + dc);
#pragma unroll
        for (int j = 0; j < 8; j++) Vt[dc + j][m] = v[j];
    }
    __syncthreads();

    int r16 = lane & 15, q4 = lane >> 4, r7 = r16 & 7;
    int kc0 = ((q4)     ^ r7) << 3;
    int kc1 = ((q4 + 4) ^ r7) << 3;
    const float s2 = 0.125f;

    {
        int nt = wave;                                     // one q-tile per wave
        f16x8 aq0 = *(const f16x8*)(base + (size_t)(nt * 16 + r16) * QKV_OC + q4 * 8);
        f16x8 aq1 = *(const f16x8*)(base + (size_t)(nt * 16 + r16) * QKV_OC + 32 + q4 * 8);
        f32x4 L[13];
#pragma unroll
        for (int mt = 0; mt < 13; ++mt) {
            const _Float16* kr = Kl + (mt * 16 + r16) * 64;
            f16x8 bk0 = *(const f16x8*)(kr + kc0);
            f16x8 bk1 = *(const f16x8*)(kr + kc1);
            f32x4 s = {0.f, 0.f, 0.f, 0.f};
            s = MFMA16(aq0, bk0, s, 0, 0, 0);
            s = MFMA16(aq1, bk1, s, 0, 0, 0);
            L[mt] = s;
        }
        float mx[4] = {-1e30f, -1e30f, -1e30f, -1e30f};
#pragma unroll
        for (int mt = 0; mt < 13; ++mt)
#pragma unroll
            for (int r = 0; r < 4; ++r) {
                float lv = L[mt][r] * s2;
                if (mt == 12 && r16 >= 4) lv = -1e30f;   // mask m >= 196
                L[mt][r] = lv;
                mx[r] = fmaxf(mx[r], lv);
            }
#pragma unroll
        for (int r = 0; r < 4; ++r)
            for (int off = 1; off < 16; off <<= 1)
                mx[r] = fmaxf(mx[r], __shfl_xor(mx[r], off));
        float sm[4] = {0.f, 0.f, 0.f, 0.f};
#pragma unroll
        for (int mt = 0; mt < 13; ++mt)
#pragma unroll
            for (int r = 0; r < 4; ++r) {
                float p = exp2f((L[mt][r] - mx[r]) * 1.44269504f);
                sm[r] += p;
                Pl[wave][q4 * 4 + r][mt * 16 + r16] = (_Float16)p;
            }
#pragma unroll
        for (int r = 0; r < 4; ++r)
            for (int off = 1; off < 16; off <<= 1)
                sm[r] += __shfl_xor(sm[r], off);

        f32x4 oacc[4];
#pragma unroll
        for (int di = 0; di < 4; ++di) oacc[di] = (f32x4){0.f, 0.f, 0.f, 0.f};
#pragma unroll
        for (int mc = 0; mc < 6; ++mc) {
            f16x8 ap = *(const f16x8*)&Pl[wave][r16][mc * 32 + q4 * 8];
#pragma unroll
            for (int di = 0; di < 4; ++di) {
                f16x8 bv = *(const f16x8*)&Vt[di * 16 + r16][mc * 32 + q4 * 8];
                oacc[di] = MFMA16(ap, bv, oacc[di], 0, 0, 0);
            }
        }
        {
            _Float16 z = (_Float16)0.f;
            f16x8 zz = (f16x8){z, z, z, z, z, z, z, z};
            f16x8 ap = (q4 < 2) ? *(const f16x8*)&Pl[wave][r16][192 + q4 * 8] : zz;
#pragma unroll
            for (int di = 0; di < 4; ++di) {
                f16x8 bv = (q4 < 2) ? *(const f16x8*)&Vt[di * 16 + r16][192 + q4 * 8] : zz;
                oacc[di] = MFMA16(ap, bv, oacc[di], 0, 0, 0);
            }
        }
#pragma unroll
        for (int r = 0; r < 4; ++r) {
            int n = nt * 16 + q4 * 4 + r;
            if (n < NPIX) {
                float rinv = 1.0f / sm[r];
                _Float16* op = Ot + (size_t)(b * NPIX + n) * CIN + h * DH + r16;
#pragma unroll
                for (int di = 0; di < 4; ++di)
                    op[di * 16] = (_Float16)(oacc[di][r] * rinv);
            }
        }
    }
}

// ---------------------------------------------------------------- launch
extern "C" void kernel_launch(void* const* d_in, const int* in_sizes, int n_in,
                              void* d_out, int out_size, void* d_ws, size_t ws_size,
                              hipStream_t stream) {
    const float* x  = (const float*)d_in[0];
    const float* wq = (const float*)d_in[1];
    const float* wp = (const float*)d_in[2];
    float* out = (float*)d_out;
    char* ws = (char*)d_ws;

    _Float16* Xt  = (_Float16*)(ws);
    _Float16* W   = (_Float16*)(ws + 20447232);
    _Float16* qkv = (_Float16*)(ws + 25165824);
    _Float16* Ot  = (_Float16*)(ws + 86507520);
    _Float16* Wq = W;
    _Float16* Wp = W + (size_t)QKV_OC * CIN;

    hipLaunchKernelGGL(k_convert_w, dim3(2304), dim3(256), 0, stream, wq, wp, W);
    hipLaunchKernelGGL(k_transpose_x, dim3(12, 64), dim3(256), 0, stream, x, Xt);
    hipLaunchKernelGGL((k_gemm2<9, 256, false>), dim3(49 * 9), dim3(512), 0, stream,
                       Xt, Wq, qkv, (float*)nullptr);
    hipLaunchKernelGGL(k_attn, dim3(768), dim3(832), 0, stream, qkv, Ot);
    hipLaunchKernelGGL((k_gemm2<4, 192, true>), dim3(49 * 4), dim3(512), 0, stream,
                       Ot, Wp, (_Float16*)nullptr, out);
}

// Round 20
// 129.883 us; speedup vs baseline: 1.0436x; 1.0106x over previous
//
#include <hip/hip_runtime.h>
#include <cstdint>
#include <cstddef>

#define NH     12
#define DH     64
#define CIN    768
#define NPIX   196
#define NB     64
#define ROWS   (NB * NPIX)      // 12544 = 49*256 = 56*224
#define QKV_OC 2304
#define NKT    12               // 768/64

typedef __attribute__((ext_vector_type(8))) _Float16 f16x8;
typedef __attribute__((ext_vector_type(4))) _Float16 f16x4;
typedef __attribute__((ext_vector_type(4))) float    f32x4;

#define MFMA16 __builtin_amdgcn_mfma_f32_16x16x32_f16

// ---------------------------------------------------------------- weights → fp16
__global__ __launch_bounds__(256) void k_convert_w(const float* __restrict__ wq,
                                                   const float* __restrict__ wp,
                                                   _Float16* __restrict__ out) {
    int i = blockIdx.x * 256 + threadIdx.x;
    const int NQ = QKV_OC * CIN / 4;
    const int NT = NQ + (CIN * CIN) / 4;
    if (i >= NT) return;
    float4 v = (i < NQ) ? ((const float4*)wq)[i] : ((const float4*)wp)[i - NQ];
    f16x4 o = { (_Float16)v.x, (_Float16)v.y, (_Float16)v.z, (_Float16)v.w };
    ((f16x4*)out)[i] = o;
}

// ------------------------------------------------- x [b][c][n] f32 → Xt [b*196+n][c] f16
__global__ __launch_bounds__(256) void k_transpose_x(const float* __restrict__ x,
                                                     _Float16* __restrict__ Xt) {
    __shared__ __align__(16) _Float16 lds[NPIX][72];
    int t  = threadIdx.x;
    int b  = blockIdx.y, c0 = blockIdx.x * 64;
    const float* xp = x + ((size_t)b * CIN + c0) * NPIX;
    for (int idx = t; idx < 64 * 49; idx += 256) {
        int c = idx / 49, k = idx - c * 49;
        float4 v = *(const float4*)(xp + (size_t)c * NPIX + k * 4);
        int n = k * 4;
        lds[n][c]     = (_Float16)v.x;
        lds[n + 1][c] = (_Float16)v.y;
        lds[n + 2][c] = (_Float16)v.z;
        lds[n + 3][c] = (_Float16)v.w;
    }
    __syncthreads();
    int cs = t & 7, nn = t >> 3;
    for (int n = nn; n < NPIX; n += 32) {
        _Float16* dst = Xt + ((size_t)(b * NPIX + n)) * CIN + c0 + cs * 8;
        *(ulonglong2*)dst = *(const ulonglong2*)&lds[n][cs * 8];
    }
}

// ---------------------------------------------------------------- helpers
__device__ inline void gload16(const _Float16* g, _Float16* l) {
    __builtin_amdgcn_global_load_lds((const __attribute__((address_space(1))) void*)g,
                                     (__attribute__((address_space(3))) void*)l,
                                     16, 0, 0);
}

// ---------------------------------------------------------------- TMxTN 2-barrier GEMM
// R15's template (harness-verified). Final combination per R15/R16 matrix:
//   QKV <9,256,256,false>: TM==256 constexpr path == frozen R0 code (131.0 e2e base)
//   proj <4,224,192,true>: one round (224 blocks <= 256 CUs) at 0.875x block work
//     (R15-verified correct; R15-vs-R16 delta shows proj-TM224 ~1us better with
//      QKV held fixed — the e2e regressions tracked QKV's TM, now reverted).
// C[r][o] = sum_c A[r][c]*B[o][c]; A:[12544][768], B:[NTN*TN][768]
// PROJ=false: C f16 [row][2304];  PROJ=true: Cf f32 out[b][col][n]
template<int NTN, int TM, int TN, bool PROJ>
__global__ __launch_bounds__(512, 2) void k_gemm2(const _Float16* __restrict__ A,
                                                  const _Float16* __restrict__ Bm,
                                                  _Float16* __restrict__ Cb,
                                                  float* __restrict__ Cf) {
    constexpr int WRH = TM / 2;        // wave row height: 128 or 112
    constexpr int RF  = WRH / 16;      // row fragments per wave: 8 or 7
    constexpr int WCW = TN / 4;        // wave col width: 64 or 48
    constexpr int CF  = WCW / 16;      // col fragments per wave: 4 or 3
    constexpr int GB  = TN / 64;       // B stage gloads per tile: 4 or 3
    __shared__ __align__(16) _Float16 As[2][256 * 64];   // 64 KiB (256-row sweep)
    __shared__ __align__(16) _Float16 Bs[2][TN * 64];    // 64 or 48 KiB
    int tid = threadIdx.x;
    int w = tid >> 6, lane = tid & 63;

    // T1: bijective XCD swizzle (handles nwg%8 != 0)
    int nwg = gridDim.x;
    int orig = blockIdx.x;
    int q = nwg >> 3, r = nwg & 7;
    int xcd = orig & 7, within = orig >> 3;
    int wg = (xcd < r ? xcd * (q + 1) : r * (q + 1) + (xcd - r) * q) + within;
    int bm = wg / NTN, bn = wg - bm * NTN;
    int m0 = bm * TM, n0 = bn * TN;

    int wr = w >> 2, wc = w & 3;          // 2 x 4 wave grid; wave tile WRH x WCW
    int r16 = lane & 15, q4 = lane >> 4;

    // staging (T2: inverse-swizzled global source; linear LDS dest)
    int sr8  = (w << 3) + (lane >> 3);                    // 0..63
    int swz8 = ((lane & 7) ^ (lane >> 3)) << 3;
    const _Float16* Ag = A  + (size_t)(m0 + sr8) * CIN + swz8;
    const _Float16* Bg = Bm + (size_t)(n0 + sr8) * CIN + swz8;

    auto stageA = [&](int buf, int kt) {
        _Float16* l0 = As[buf] + (w << 9);
        if constexpr (TM == 256) {
            const _Float16* g = Ag + kt * 64;
            gload16(g,             l0);
            gload16(g +  64 * CIN, l0 + 4096);
            gload16(g + 128 * CIN, l0 + 8192);
            gload16(g + 192 * CIN, l0 + 12288);
        } else {
#pragma unroll
            for (int s = 0; s < 4; s++) {
                int row = m0 + sr8 + s * 64;
                if (row > ROWS - 1) row = ROWS - 1;   // clamp: lands in LDS rows >= TM, never read
                gload16(A + (size_t)row * CIN + swz8 + kt * 64, l0 + s * 4096);
            }
        }
    };
    auto stageB = [&](int buf, int kt) {
        const _Float16* g = Bg + kt * 64;
        _Float16* l0 = Bs[buf] + (w << 9);
        gload16(g,             l0);
        gload16(g +  64 * CIN, l0 + 4096);
        gload16(g + 128 * CIN, l0 + 8192);
        if constexpr (GB == 4) gload16(g + 192 * CIN, l0 + 12288);
    };

    // counted-vmcnt invariant: outstanding at tile end = (4+GB) loads of t+2;
    // waiting (4+GB) drains tile t+1. In-order VMEM queue (m135).
#define VM_WAIT_N() do { if constexpr (GB == 4) { asm volatile("s_waitcnt vmcnt(8)" ::: "memory"); } \
                         else                   { asm volatile("s_waitcnt vmcnt(7)" ::: "memory"); } } while (0)

    int cS0 = ((q4)     ^ (r16 & 7)) << 3;
    int cS1 = ((q4 + 4) ^ (r16 & 7)) << 3;

    f32x4 acc[RF][CF];
#pragma unroll
    for (int i = 0; i < RF; i++)
#pragma unroll
        for (int j = 0; j < CF; j++) acc[i][j] = (f32x4){0.f, 0.f, 0.f, 0.f};

    // prologue
    stageA(0, 0); stageB(0, 0);
    stageA(1, 1); stageB(1, 1);
    VM_WAIT_N();
    __builtin_amdgcn_sched_barrier(0);
    __builtin_amdgcn_s_barrier();

#pragma unroll 2
    for (int t = 0; t < NKT; ++t) {
        int bt = t & 1;
        const _Float16* Ab = As[bt] + (wr * WRH + r16) * 64;
        const _Float16* Bb = Bs[bt] + (wc * WCW + r16) * 64;
        bool pre = (t + 2 < NKT);

        // read all fragments for this K-tile (2*RF A + 2*CF B ds_read_b128)
        f16x8 a[RF][2], bb[CF][2];
#pragma unroll
        for (int i = 0; i < RF; i++) {
            a[i][0] = *(const f16x8*)(Ab + (i << 10) + cS0);
            a[i][1] = *(const f16x8*)(Ab + (i << 10) + cS1);
        }
#pragma unroll
        for (int g = 0; g < CF; g++) {
            bb[g][0] = *(const f16x8*)(Bb + (g << 10) + cS0);
            bb[g][1] = *(const f16x8*)(Bb + (g << 10) + cS1);
        }

        // MFMA burst 1: col fragments 0,1
        __builtin_amdgcn_s_setprio(1);
#pragma unroll
        for (int i = 0; i < RF; i++)
#pragma unroll
            for (int g = 0; g < 2; g++) {
                acc[i][g] = MFMA16(a[i][0], bb[g][0], acc[i][g], 0, 0, 0);
                acc[i][g] = MFMA16(a[i][1], bb[g][1], acc[i][g], 0, 0, 0);
            }
        __builtin_amdgcn_s_setprio(0);

        // all reads of buffer bt complete for every wave at this barrier
        asm volatile("s_waitcnt lgkmcnt(0)" ::: "memory");
        __builtin_amdgcn_sched_barrier(0);
        __builtin_amdgcn_s_barrier();

        // stage tile t+2 into the buffer we just finished reading
        if (pre) { stageA(bt, t + 2); stageB(bt, t + 2); }

        // MFMA burst 2: col fragments 2..CF-1
        __builtin_amdgcn_s_setprio(1);
#pragma unroll
        for (int i = 0; i < RF; i++)
#pragma unroll
            for (int g = 2; g < CF; g++) {
                acc[i][g] = MFMA16(a[i][0], bb[g][0], acc[i][g], 0, 0, 0);
                acc[i][g] = MFMA16(a[i][1], bb[g][1], acc[i][g], 0, 0, 0);
            }
        __builtin_amdgcn_s_setprio(0);

        // tile t+1 must be resident before next iteration's reads
        if (pre) { VM_WAIT_N(); }
        else     { asm volatile("s_waitcnt vmcnt(0)" ::: "memory"); }
        __builtin_amdgcn_sched_barrier(0);
        __builtin_amdgcn_s_barrier();
    }
#undef VM_WAIT_N

    if (!PROJ) {
#pragma unroll
        for (int i = 0; i < RF; i++)
#pragma unroll
            for (int rr = 0; rr < 4; rr++) {
                int row = m0 + wr * WRH + i * 16 + q4 * 4 + rr;
                _Float16* cp = Cb + (size_t)row * QKV_OC + n0 + wc * WCW + r16;
#pragma unroll
                for (int ct = 0; ct < CF; ct++)
                    cp[ct * 16] = (_Float16)acc[i][ct][rr];
            }
    } else {
#pragma unroll
        for (int i = 0; i < RF; i++) {
            int row = m0 + wr * WRH + i * 16 + q4 * 4;     // multiple of 4
            int b = row / NPIX;
            int n = row - b * NPIX;                         // 196%4==0: no straddle
#pragma unroll
            for (int ct = 0; ct < CF; ct++) {
                int col = n0 + wc * WCW + ct * 16 + r16;
                f32x4 v = acc[i][ct];
                float4 o; o.x = v[0]; o.y = v[1]; o.z = v[2]; o.w = v[3];
                *(float4*)(Cf + ((size_t)b * CIN + col) * NPIX + n) = o;
            }
        }
    }
}

// ---------------------------------------------------------------- fused attention
// R9 BEST-VERIFIED VERSION (verbatim; 133.8-134.0us across three runs).
// 832 threads = 13 waves per (b,h) block: one q-tile per wave (serial depth 1),
// 3.25 waves/SIMD. LDS 144128 B, 1 block/CU, grid 768 = 3 rounds.
__global__ __launch_bounds__(832) void k_attn(const _Float16* __restrict__ qkv,
                                              _Float16* __restrict__ Ot) {
    __shared__ __align__(16) _Float16 Kl[208 * 64];
    __shared__ __align__(16) _Float16 Vt[64][216];
    __shared__ __align__(16) _Float16 Pl[13][16][216];
    int tid = threadIdx.x, wave = tid >> 6, lane = tid & 63;
    int bh = blockIdx.x;
    int b = bh / NH, h = bh - b * NH;
    const _Float16* base  = qkv + (size_t)b * NPIX * QKV_OC + h * DH;  // Q
    const _Float16* kb    = base + CIN;                                 // K
    const _Float16* vbase = base + 2 * CIN;                             // V

    {
        int c8 = lane & 7;
#pragma unroll
        for (int rr = 0; rr < 2; ++rr) {
            int grp = wave + rr * 13;                       // 0..25 exactly
            int row = grp * 8 + (lane >> 3);
            const _Float16* src = kb + (size_t)row * QKV_OC + ((c8 ^ (row & 7)) << 3);
            gload16(src, Kl + row * 64 + (c8 << 3));
        }
    }
    for (int task = tid; task < 208 * 8; task += 832) {    // 2 iterations exactly
        int m = task >> 3, dc = (task & 7) * 8;
        f16x8 v = *(const f16x8*)(vbase + (size_t)m * QKV_OC + dc);
#pragma unroll
        for (int j = 0; j < 8; j++) Vt[dc + j][m] = v[j];
    }
    __syncthreads();

    int r16 = lane & 15, q4 = lane >> 4, r7 = r16 & 7;
    int kc0 = ((q4)     ^ r7) << 3;
    int kc1 = ((q4 + 4) ^ r7) << 3;
    const float s2 = 0.125f;

    {
        int nt = wave;                                     // one q-tile per wave
        f16x8 aq0 = *(const f16x8*)(base + (size_t)(nt * 16 + r16) * QKV_OC + q4 * 8);
        f16x8 aq1 = *(const f16x8*)(base + (size_t)(nt * 16 + r16) * QKV_OC + 32 + q4 * 8);
        f32x4 L[13];
#pragma unroll
        for (int mt = 0; mt < 13; ++mt) {
            const _Float16* kr = Kl + (mt * 16 + r16) * 64;
            f16x8 bk0 = *(const f16x8*)(kr + kc0);
            f16x8 bk1 = *(const f16x8*)(kr + kc1);
            f32x4 s = {0.f, 0.f, 0.f, 0.f};
            s = MFMA16(aq0, bk0, s, 0, 0, 0);
            s = MFMA16(aq1, bk1, s, 0, 0, 0);
            L[mt] = s;
        }
        float mx[4] = {-1e30f, -1e30f, -1e30f, -1e30f};
#pragma unroll
        for (int mt = 0; mt < 13; ++mt)
#pragma unroll
            for (int r = 0; r < 4; ++r) {
                float lv = L[mt][r] * s2;
                if (mt == 12 && r16 >= 4) lv = -1e30f;   // mask m >= 196
                L[mt][r] = lv;
                mx[r] = fmaxf(mx[r], lv);
            }
#pragma unroll
        for (int r = 0; r < 4; ++r)
            for (int off = 1; off < 16; off <<= 1)
                mx[r] = fmaxf(mx[r], __shfl_xor(mx[r], off));
        float sm[4] = {0.f, 0.f, 0.f, 0.f};
#pragma unroll
        for (int mt = 0; mt < 13; ++mt)
#pragma unroll
            for (int r = 0; r < 4; ++r) {
                float p = exp2f((L[mt][r] - mx[r]) * 1.44269504f);
                sm[r] += p;
                Pl[wave][q4 * 4 + r][mt * 16 + r16] = (_Float16)p;
            }
#pragma unroll
        for (int r = 0; r < 4; ++r)
            for (int off = 1; off < 16; off <<= 1)
                sm[r] += __shfl_xor(sm[r], off);

        f32x4 oacc[4];
#pragma unroll
        for (int di = 0; di < 4; ++di) oacc[di] = (f32x4){0.f, 0.f, 0.f, 0.f};
#pragma unroll
        for (int mc = 0; mc < 6; ++mc) {
            f16x8 ap = *(const f16x8*)&Pl[wave][r16][mc * 32 + q4 * 8];
#pragma unroll
            for (int di = 0; di < 4; ++di) {
                f16x8 bv = *(const f16x8*)&Vt[di * 16 + r16][mc * 32 + q4 * 8];
                oacc[di] = MFMA16(ap, bv, oacc[di], 0, 0, 0);
            }
        }
        {
            _Float16 z = (_Float16)0.f;
            f16x8 zz = (f16x8){z, z, z, z, z, z, z, z};
            f16x8 ap = (q4 < 2) ? *(const f16x8*)&Pl[wave][r16][192 + q4 * 8] : zz;
#pragma unroll
            for (int di = 0; di < 4; ++di) {
                f16x8 bv = (q4 < 2) ? *(const f16x8*)&Vt[di * 16 + r16][192 + q4 * 8] : zz;
                oacc[di] = MFMA16(ap, bv, oacc[di], 0, 0, 0);
            }
        }
#pragma unroll
        for (int r = 0; r < 4; ++r) {
            int n = nt * 16 + q4 * 4 + r;
            if (n < NPIX) {
                float rinv = 1.0f / sm[r];
                _Float16* op = Ot + (size_t)(b * NPIX + n) * CIN + h * DH + r16;
#pragma unroll
                for (int di = 0; di < 4; ++di)
                    op[di * 16] = (_Float16)(oacc[di][r] * rinv);
            }
        }
    }
}

// ---------------------------------------------------------------- launch
extern "C" void kernel_launch(void* const* d_in, const int* in_sizes, int n_in,
                              void* d_out, int out_size, void* d_ws, size_t ws_size,
                              hipStream_t stream) {
    const float* x  = (const float*)d_in[0];
    const float* wq = (const float*)d_in[1];
    const float* wp = (const float*)d_in[2];
    float* out = (float*)d_out;
    char* ws = (char*)d_ws;

    _Float16* Xt  = (_Float16*)(ws);
    _Float16* W   = (_Float16*)(ws + 20447232);
    _Float16* qkv = (_Float16*)(ws + 25165824);
    _Float16* Ot  = (_Float16*)(ws + 86507520);
    _Float16* Wq = W;
    _Float16* Wp = W + (size_t)QKV_OC * CIN;

    hipLaunchKernelGGL(k_convert_w, dim3(2304), dim3(256), 0, stream, wq, wp, W);
    hipLaunchKernelGGL(k_transpose_x, dim3(12, 64), dim3(256), 0, stream, x, Xt);
    hipLaunchKernelGGL((k_gemm2<9, 256, 256, false>), dim3(49 * 9), dim3(512), 0, stream,
                       Xt, Wq, qkv, (float*)nullptr);
    hipLaunchKernelGGL(k_attn, dim3(768), dim3(832), 0, stream, qkv, Ot);
    hipLaunchKernelGGL((k_gemm2<4, 224, 192, true>), dim3(56 * 4), dim3(512), 0, stream,
                       Ot, Wp, (_Float16*)nullptr, out);
}